// Round 12
// baseline (730.505 us; speedup 1.0000x reference)
//
#include <hip/hip_runtime.h>
#include <math.h>

#define B_    8
#define K_    8
#define C_    128
#define HW_   4096
#define NUM_  2048
#define N_    7          // K-1 refs used

// ---------------- workspace layout (32-bit words) ----------------
#define WS_A_OFF    0                               // [B][NUM][C] raw q
#define WS_INV_OFF  (B_*NUM_*C_)                    // [B][K][HW] 1/norm
#define WS_KBUF_OFF (WS_INV_OFF + B_*K_*HW_)        // [B][N][NUM][2] uint4
#define WS_IDX_OFF  (WS_KBUF_OFF + B_*N_*NUM_*8)    // [B][N][NUM] int
#define WS_A2_OFF   (WS_IDX_OFF + B_*N_*NUM_)       // [B][NUM][C] normed q
#define WS_GHI_OFF  (WS_A2_OFF + B_*NUM_*C_)        // pre-split planes
#define GPLANE_V4   (B_*K_*16*HW_)                  // u32x4 per plane

typedef __bf16 bf16x8 __attribute__((ext_vector_type(8)));
typedef float  f32x4  __attribute__((ext_vector_type(4)));
typedef unsigned int u32x4 __attribute__((ext_vector_type(4)));

static __device__ __forceinline__ f32x4 mf16(bf16x8 a, bf16x8 b, f32x4 c) {
    return __builtin_amdgcn_mfma_f32_16x16x32_bf16(a, b, c, 0, 0, 0);
}

// RTNE bf16 high-part (bit math, branch-free)
static __device__ __forceinline__ unsigned bfhi16(float x) {
    unsigned b = __float_as_uint(x);
    return (b + 0x7fffu + ((b >> 16) & 1u)) >> 16;
}
// split two floats (consecutive c) into packed hi-pair and lo-pair u32
static __device__ __forceinline__ void split2(float x, float y,
                                              unsigned &hp, unsigned &lp) {
    unsigned hx = bfhi16(x), hy = bfhi16(y);
    float rx = x - __uint_as_float(hx << 16);
    float ry = y - __uint_as_float(hy << 16);
    hp = hx | (hy << 16);
    lp = bfhi16(rx) | (bfhi16(ry) << 16);
}

// ---- contraction-proof mul/add (verbatim from the passing round-6 kernel)
static __device__ __forceinline__ float fmul_nc(float a, float b) {
    float r = a * b;
    asm volatile("" : "+v"(r));
    return r;
}
static __device__ __forceinline__ float fadd_nc(float a, float b) {
    float r = a + b;
    asm volatile("" : "+v"(r));
    return r;
}

// async global -> LDS, 16B per lane
static __device__ __forceinline__ void gll16(const u32x4* g, u32x4* l) {
    __builtin_amdgcn_global_load_lds(
        (const __attribute__((address_space(1))) void*)g,
        (__attribute__((address_space(3))) void*)l, 16, 0, 0);
}

// ---------------------------------------------------------------------------
// Kernel 0 (FUSED norm + presplit): one thread per (bk,h) loads the whole
// 128-c column (coalesced across h), computes inv = 1/max(||col||,1e-12),
// writes inv AND both normalized split planes. refs read ONCE (was twice).
// ---------------------------------------------------------------------------
__global__ void norm_presplit(const float* __restrict__ refs,
                              float* __restrict__ inv,
                              u32x4* __restrict__ Ghi,
                              u32x4* __restrict__ Glo) {
    int i = blockIdx.x * blockDim.x + threadIdx.x;   // over B*K*HW
    int h  = i & (HW_ - 1);
    int bk = i >> 12;
    const float* p = refs + (size_t)bk * C_ * HW_ + h;
    float v[C_];
#pragma unroll
    for (int c = 0; c < C_; ++c) v[c] = p[(size_t)c * HW_];
    float ss = 0.f;
#pragma unroll
    for (int c = 0; c < C_; ++c) ss = fmaf(v[c], v[c], ss);
    float iv = 1.0f / fmaxf(sqrtf(ss), 1e-12f);
    inv[i] = iv;
#pragma unroll
    for (int cg = 0; cg < 16; ++cg) {
        u32x4 H, L;
#pragma unroll
        for (int m = 0; m < 4; ++m) {
            unsigned hp, lp;
            split2(v[cg * 8 + 2 * m] * iv, v[cg * 8 + 2 * m + 1] * iv, hp, lp);
            H[m] = hp; L[m] = lp;
        }
        size_t o = (size_t)(bk * 16 + cg) * HW_ + h;
        Ghi[o] = H;
        Glo[o] = L;
    }
}

// ---------------------------------------------------------------------------
// Kernel 2: gather query vectors; write raw (A, for emul/fuse) and
// L2-normalized (A2, for the GEMM — per-q positive scale, argmax-invariant).
// ---------------------------------------------------------------------------
__global__ void aprep2_kernel(const float* __restrict__ feat,
                              const int* __restrict__ fidx,
                              float* __restrict__ A,
                              float* __restrict__ A2) {
    int w    = (blockIdx.x * blockDim.x + threadIdx.x) >> 6;  // bq
    int lane = threadIdx.x & 63;
    int fi = fidx[w];
    int b  = w >> 11;
    const float* src = feat + (size_t)b * C_ * HW_ + fi;
    float v0 = src[(size_t)lane * HW_];
    float v1 = src[(size_t)(lane + 64) * HW_];
    float ss = fmaf(v0, v0, v1 * v1);
#pragma unroll
    for (int off = 32; off; off >>= 1) ss += __shfl_xor(ss, off);
    float rn = 1.0f / fmaxf(sqrtf(ss), 1e-12f);
    size_t o = (size_t)w * C_;
    A[o + lane]       = v0;
    A[o + lane + 64]  = v1;
    A2[o + lane]      = v0 * rn;
    A2[o + lane + 64] = v1 * rn;
}

// ---------------------------------------------------------------------------
// Kernel 3: split-bf16 3-pass MFMA GEMM, h-SPLIT: each block covers half
// the h-range (2048) of one (pair, q-tile) -> grid 1792, 64 iters, ~5
// blocks/CU co-resident (was grid-capped at 3.5). Per half: per-lane
// packed-key top-2 + 16-lane bitonic -> top-4 keys written as uint4.
// ---------------------------------------------------------------------------
__global__ __launch_bounds__(256, 4) void gemm_gll_topk2(
        const float* __restrict__ A2,
        const u32x4* __restrict__ Ghi, const u32x4* __restrict__ Glo,
        const int* __restrict__ pindex,
        uint4* __restrict__ kbuf) {
    __shared__ u32x4 Bsh[2][2][512];   // 32 KiB: [buf][plane][cg*32+h]

    const int tid = threadIdx.x;
    const int l = tid & 63, wq = tid >> 6;
    const int ll = l & 15, lh = l >> 4;

    // XCD swizzle: 224 consecutive work-ids (7 pairs x 32 subtiles) per XCD
    int bid = blockIdx.x;
    int swz = (bid & 7) * 224 + (bid >> 3);
    int pair = swz >> 5;
    int rem  = swz & 31;
    int qt = rem >> 1, hs = rem & 1;
    int b = pair / N_, n = pair % N_;
    int index = pindex[0];
    int ks = n + (n >= index ? 1 : 0);
    const int hbase0 = hs * 2048;

    const float* Ap = A2 + ((size_t)b * NUM_ + qt * 128 + wq * 32) * C_;
    const u32x4* Gh = Ghi + (size_t)(b * K_ + ks) * 16 * HW_ + hbase0;
    const u32x4* Gl = Glo + (size_t)(b * K_ + ks) * 16 * HW_ + hbase0;

    // ---- A fragments (hi/lo split of normalized q), persistent ----
    bf16x8 ahi[2][4], alo[2][4];
#pragma unroll
    for (int mf = 0; mf < 2; ++mf)
#pragma unroll
        for (int kk = 0; kk < 4; ++kk) {
            const float* ap = Ap + (mf * 16 + ll) * C_ + kk * 32 + lh * 8;
            float4 xa = *(const float4*)ap;
            float4 xb = *(const float4*)(ap + 4);
            float xs[8] = {xa.x, xa.y, xa.z, xa.w, xb.x, xb.y, xb.z, xb.w};
            u32x4 H, L;
#pragma unroll
            for (int p = 0; p < 4; ++p) {
                unsigned hp, lp;
                split2(xs[2*p], xs[2*p+1], hp, lp);
                H[p] = hp; L[p] = lp;
            }
            ahi[mf][kk] = __builtin_bit_cast(bf16x8, H);
            alo[mf][kk] = __builtin_bit_cast(bf16x8, L);
        }

    // ---- per-lane packed-key top-2 per q-row (8 rows) ----
    unsigned k1[8], k2[8];
#pragma unroll
    for (int rw = 0; rw < 8; ++rw) { k1[rw] = 0u; k2[rw] = 0u; }

    // ---- gll staging map: call j stages linear idx j*256+tid ----
    const int lin0 = tid, lin1 = 256 + tid;
    const size_t go0 = (size_t)(lin0 >> 5) * HW_ + (lin0 & 31);
    const size_t go1 = (size_t)(lin1 >> 5) * HW_ + (lin1 & 31);

#define STAGE(buf, htv) do {                                   \
        gll16(Gh + go0 + (htv), &Bsh[buf][0][lin0]);           \
        gll16(Gh + go1 + (htv), &Bsh[buf][0][lin1]);           \
        gll16(Gl + go0 + (htv), &Bsh[buf][1][lin0]);           \
        gll16(Gl + go1 + (htv), &Bsh[buf][1][lin1]);           \
    } while (0)

    STAGE(0, 0);
    __syncthreads();   // vmcnt(0) drain inserted by compiler

    for (int t = 0; t < 64; ++t) {
        const int cur = t & 1;
        const int ht = t * 32;

        // issue next tile into the other buffer; ages behind MFMA below
        if (t < 63) STAGE(cur ^ 1, ht + 32);

        // ---- 3-pass MFMA: acc = 6 + Ah*Bh + Ah*Bl + Al*Bh ----
        f32x4 acc[2][2];
#pragma unroll
        for (int mf = 0; mf < 2; ++mf)
#pragma unroll
            for (int nf = 0; nf < 2; ++nf) acc[mf][nf] = 6.0f;

#pragma unroll
        for (int kk = 0; kk < 4; ++kk) {
#pragma unroll
            for (int nf = 0; nf < 2; ++nf) {
                int off = (kk * 4 + lh) * 32 + nf * 16 + ll;
                bf16x8 bh = __builtin_bit_cast(bf16x8, Bsh[cur][0][off]);
                bf16x8 bl = __builtin_bit_cast(bf16x8, Bsh[cur][1][off]);
#pragma unroll
                for (int mf = 0; mf < 2; ++mf) {
                    f32x4 a_ = acc[mf][nf];
                    a_ = mf16(ahi[mf][kk], bh, a_);
                    a_ = mf16(ahi[mf][kk], bl, a_);
                    a_ = mf16(alo[mf][kk], bh, a_);
                    acc[mf][nf] = a_;
                }
            }
        }

        // ---- packed-key top-2 (branchless, 5 VALU/elem) ----
#pragma unroll
        for (int nf = 0; nf < 2; ++nf) {
            unsigned hv = (unsigned)(hbase0 + ht + nf * 16 + ll);
#pragma unroll
            for (int mf = 0; mf < 2; ++mf)
#pragma unroll
                for (int r = 0; r < 4; ++r) {
                    int rw = mf * 4 + r;
                    unsigned u = __float_as_uint(acc[mf][nf][r]);
                    unsigned key = ((u & 0x007FFFF8u) << 9) | hv;
                    unsigned mn = min(k1[rw], key);
                    k1[rw] = max(k1[rw], key);
                    k2[rw] = max(k2[rw], mn);
                }
        }

        __syncthreads();   // next tile staged + all reads of cur done
    }
#undef STAGE

    // ---- 16-lane bitonic merge of (k1,k2) -> per-half top-4 keys ----
#define CEU(X,Y) { if (mv[Y] > mv[X]) { unsigned t_ = mv[X]; mv[X] = mv[Y]; mv[Y] = t_; } }
#pragma unroll
    for (int rw = 0; rw < 8; ++rw) {
        unsigned av[4] = {k1[rw], k2[rw], 0u, 0u};
#pragma unroll
        for (int s = 1; s <= 8; s <<= 1) {
            unsigned bv[4];
#pragma unroll
            for (int j = 0; j < 4; ++j)
                bv[j] = (unsigned)__shfl_xor((int)av[j], s);
            unsigned mv[4];
#pragma unroll
            for (int j = 0; j < 4; ++j)
                mv[j] = (av[j] > bv[3-j]) ? av[j] : bv[3-j];
            CEU(0, 2) CEU(1, 3) CEU(0, 1) CEU(2, 3)
#pragma unroll
            for (int j = 0; j < 4; ++j) av[j] = mv[j];
        }
        if (ll == 0) {
            int q = qt * 128 + wq * 32 + (rw >> 2) * 16 + lh * 4 + (rw & 3);
            size_t o = ((size_t)(b * N_ + n) * NUM_ + q) * 2 + hs;
            kbuf[o] = make_uint4(av[0], av[1], av[2], av[3]);
        }
    }
#undef CEU
}

// ---------------------------------------------------------------------------
// numpy pairwise sum (n=128) — verbatim rounding from the passing round-6
// kernel.
// ---------------------------------------------------------------------------
static __device__ float pairwise128_sumsq_div(const float* __restrict__ x,
                                              float d) {
    float r[8];
#pragma unroll
    for (int j = 0; j < 8; ++j) {
        float v = __fdiv_rn(x[j], d);
        r[j] = fmul_nc(v, v);
    }
    for (int i = 8; i < C_; i += 8) {
#pragma unroll
        for (int j = 0; j < 8; ++j) {
            float v = __fdiv_rn(x[i + j], d);
            r[j] = fadd_nc(r[j], fmul_nc(v, v));
        }
    }
    return fadd_nc(fadd_nc(fadd_nc(r[0], r[1]), fadd_nc(r[2], r[3])),
                   fadd_nc(fadd_nc(r[4], r[5]), fadd_nc(r[6], r[7])));
}

// ---------------------------------------------------------------------------
// Emulated numpy score — arithmetic verbatim from round 6; ref column is
// batch-loaded into registers first (one L3 latency, not 128 serial).
// ---------------------------------------------------------------------------
static __device__ float emul_score_batched(const float* __restrict__ w2a,
                                           const float* __restrict__ Rb,
                                           int h) {
    float rv[C_];
#pragma unroll
    for (int c = 0; c < C_; ++c) rv[c] = Rb[(size_t)c * HW_ + h];
    float sr = fmul_nc(rv[0], rv[0]);
#pragma unroll
    for (int c = 1; c < C_; ++c)
        sr = fadd_nc(sr, fmul_nc(rv[c], rv[c]));    // non-FMA, ascending c
    float nr = fmaxf(__fsqrt_rn(sr), 1e-12f);
    float acc = 0.f;
#pragma unroll
    for (int c = 0; c < C_; ++c) {
        float wr = __fdiv_rn(rv[c], nr);
        acc = fadd_nc(acc, fmul_nc(w2a[c], wr));    // non-FMA, ascending c
    }
    return acc;
}

// ---------------------------------------------------------------------------
// Kernel 3b: adjudicate the union of both halves' top-4 (8 candidates).
// Prune when global key gap decisive; else exact numpy emulation of all 8,
// lowest-index tie-break.
// ---------------------------------------------------------------------------
__global__ __launch_bounds__(256, 1) void rescore_emul8(
        const float* __restrict__ A,
        const float* __restrict__ refs,
        const int* __restrict__ pindex,
        const uint4* __restrict__ kbuf,
        float thr,
        int* __restrict__ idxout,
        float* __restrict__ out2) {
    int r = blockIdx.x * blockDim.x + threadIdx.x;   // over B*N*NUM
    if (r >= B_ * N_ * NUM_) return;
    uint4 ka = kbuf[(size_t)r * 2 + 0];
    uint4 kb = kbuf[(size_t)r * 2 + 1];
    unsigned kk[8] = {ka.x, ka.y, ka.z, ka.w, kb.x, kb.y, kb.z, kb.w};
    unsigned s1 = 0u, s2 = 0u;
#pragma unroll
    for (int j = 0; j < 8; ++j) {
        unsigned mn = min(s1, kk[j]);
        s1 = max(s1, kk[j]);
        s2 = max(s2, mn);
    }
    int win;
    if ((float)((s1 >> 12) - (s2 >> 12)) > thr) {
        win = (int)(s1 & 0xFFFu);
    } else {
        int q  = r & (NUM_ - 1);
        int bn = r >> 11;
        int b = bn / N_, n = bn % N_;
        int index = pindex[0];
        int ks = n + (n >= index ? 1 : 0);
        const float* qp = A    + ((size_t)b * NUM_ + q) * C_;
        const float* Rb = refs + (size_t)(b * K_ + ks) * C_ * HW_;
        float s1f = pairwise128_sumsq_div(qp, 1.0f);
        float n1 = fmaxf(__fsqrt_rn(s1f), 1e-12f);
        float s2f = pairwise128_sumsq_div(qp, n1);
        float n2 = fmaxf(__fsqrt_rn(s2f), 1e-12f);
        // hoist double-normalized query (verbatim rounding), reuse 8x
        float w2a[C_];
#pragma unroll
        for (int c = 0; c < C_; ++c)
            w2a[c] = __fdiv_rn(__fdiv_rn(qp[c], n1), n2);
        win = (int)(kk[0] & 0xFFFu);
        float bw = emul_score_batched(w2a, Rb, win);
        for (int j = 1; j < 8; ++j) {
            int h = (int)(kk[j] & 0xFFFu);
            float s = emul_score_batched(w2a, Rb, h);
            if (s > bw || (s == bw && h < win)) { bw = s; win = h; }
        }
    }
    idxout[r] = win;
    out2[r]   = (float)win;
}

// ---------------------------------------------------------------------------
// Kernel 4: fused = base_sim*feat_sel + sum_n sims[n]*refs[b,kn,:,idx_n],
// scattered into out[b][c][fi]. Also writes feat_indices output as float.
// ---------------------------------------------------------------------------
__global__ void fuse_scatter(const float* __restrict__ A,
                             const float* __restrict__ refs,
                             const float* __restrict__ sim,
                             const int* __restrict__ fidx,
                             const int* __restrict__ pindex,
                             const int* __restrict__ idxbuf,
                             float* __restrict__ out0,
                             float* __restrict__ out1) {
    int bq = blockIdx.x;                 // over B*NUM
    int q  = bq & (NUM_ - 1);
    int b  = bq >> 11;
    int c  = threadIdx.x;                // 128 threads
    int index = pindex[0];
    int fi = fidx[bq];

    float v = sim[b * K_ + index] * A[(size_t)bq * C_ + c];
#pragma unroll
    for (int n = 0; n < N_; ++n) {
        int ks = n + (n >= index ? 1 : 0);
        int id = idxbuf[(size_t)(b * N_ + n) * NUM_ + q];
        v = fmaf(sim[b * K_ + ks],
                 refs[((size_t)(b * K_ + ks) * C_ + c) * HW_ + id], v);
    }
    out0[((size_t)b * C_ + c) * HW_ + fi] = v;
    if (c == 0) out1[bq] = (float)fi;
}

// ---------------------------------------------------------------------------
extern "C" void kernel_launch(void* const* d_in, const int* in_sizes, int n_in,
                              void* d_out, int out_size, void* d_ws, size_t ws_size,
                              hipStream_t stream) {
    const float* feat = (const float*)d_in[0];   // [B][C][HW]
    const float* refs = (const float*)d_in[1];   // [B][K][C][HW]
    const float* sim  = (const float*)d_in[2];   // [B][K]
    const int*   fidx = (const int*)d_in[3];     // [B][NUM]
    const int*   pidx = (const int*)d_in[4];     // scalar index

    float* wsf   = (float*)d_ws;
    float* A     = wsf + WS_A_OFF;
    float* inv   = wsf + WS_INV_OFF;
    uint4* kbuf  = (uint4*)(wsf + WS_KBUF_OFF);
    int*   idxf  = (int*)(wsf + WS_IDX_OFF);
    float* A2    = wsf + WS_A2_OFF;
    u32x4* Ghi   = (u32x4*)(wsf + WS_GHI_OFF);
    u32x4* Glo   = Ghi + GPLANE_V4;

    float* out0 = (float*)d_out;                       // [B][C][HW]
    float* out1 = out0 + (size_t)B_ * C_ * HW_;        // feat_indices (f32)
    float* out2 = out1 + (size_t)B_ * NUM_;            // ref_indices (f32)

    // fused inverse-norm + normalized split planes (refs read once)
    norm_presplit<<<(B_ * K_ * HW_) / 256, 256, 0, stream>>>(
        refs, inv, Ghi, Glo);
    aprep2_kernel<<<(B_ * NUM_) / 4, 256, 0, stream>>>(feat, fidx, A, A2);
    hipMemcpyAsync(out0, feat, (size_t)B_ * C_ * HW_ * sizeof(float),
                   hipMemcpyDeviceToDevice, stream);
    // h-split GEMM: 56 pairs x 16 q-tiles x 2 h-halves
    gemm_gll_topk2<<<56 * 16 * 2, 256, 0, stream>>>(A2, Ghi, Glo, pidx, kbuf);
    // prune threshold: 8.5 key units ~ 3.2e-5 in cosine scale
    rescore_emul8<<<(B_ * N_ * NUM_ + 255) / 256, 256, 0, stream>>>(
        A, refs, pidx, kbuf, 8.5f, idxf, out2);
    fuse_scatter<<<B_ * NUM_, 128, 0, stream>>>(A, refs, sim, fidx, pidx,
                                                idxf, out0, out1);
}

// Round 13
// 670.316 us; speedup vs baseline: 1.0898x; 1.0898x over previous
//
#include <hip/hip_runtime.h>
#include <math.h>

#define B_    8
#define K_    8
#define C_    128
#define HW_   4096
#define NUM_  2048
#define N_    7          // K-1 refs used

// ---------------- workspace layout (32-bit words) ----------------
#define WS_A_OFF    0                               // [B][NUM][C] raw q
#define WS_INV_OFF  (B_*NUM_*C_)                    // [B][K][HW] 1/norm
#define WS_KBUF_OFF (WS_INV_OFF + B_*K_*HW_)        // [B][N][NUM][2] uint4
#define WS_IDX_OFF  (WS_KBUF_OFF + B_*N_*NUM_*8)    // [B][N][NUM] int
#define WS_A2_OFF   (WS_IDX_OFF + B_*N_*NUM_)       // [B][NUM][C] normed q
#define WS_GHI_OFF  (WS_A2_OFF + B_*NUM_*C_)        // pre-split planes
#define GPLANE_V4   (B_*K_*16*HW_)                  // u32x4 per plane

typedef __bf16 bf16x8 __attribute__((ext_vector_type(8)));
typedef float  f32x4  __attribute__((ext_vector_type(4)));
typedef unsigned int u32x4 __attribute__((ext_vector_type(4)));

static __device__ __forceinline__ f32x4 mf16(bf16x8 a, bf16x8 b, f32x4 c) {
    return __builtin_amdgcn_mfma_f32_16x16x32_bf16(a, b, c, 0, 0, 0);
}

// RTNE bf16 high-part (bit math, branch-free)
static __device__ __forceinline__ unsigned bfhi16(float x) {
    unsigned b = __float_as_uint(x);
    return (b + 0x7fffu + ((b >> 16) & 1u)) >> 16;
}
// split two floats (consecutive c) into packed hi-pair and lo-pair u32
static __device__ __forceinline__ void split2(float x, float y,
                                              unsigned &hp, unsigned &lp) {
    unsigned hx = bfhi16(x), hy = bfhi16(y);
    float rx = x - __uint_as_float(hx << 16);
    float ry = y - __uint_as_float(hy << 16);
    hp = hx | (hy << 16);
    lp = bfhi16(rx) | (bfhi16(ry) << 16);
}

// ---- contraction-proof mul/add (verbatim from the passing round-6 kernel)
static __device__ __forceinline__ float fmul_nc(float a, float b) {
    float r = a * b;
    asm volatile("" : "+v"(r));
    return r;
}
static __device__ __forceinline__ float fadd_nc(float a, float b) {
    float r = a + b;
    asm volatile("" : "+v"(r));
    return r;
}

// async global -> LDS, 16B per lane
static __device__ __forceinline__ void gll16(const u32x4* g, u32x4* l) {
    __builtin_amdgcn_global_load_lds(
        (const __attribute__((address_space(1))) void*)g,
        (__attribute__((address_space(3))) void*)l, 16, 0, 0);
}

// ---------------------------------------------------------------------------
// Kernel 1: inverse L2 norms, float4-vectorized (each thread: 4 h columns).
// 16B/lane loads = coalescing sweet spot (G13).
// ---------------------------------------------------------------------------
__global__ void norm_kernel(const float* __restrict__ refs,
                            float* __restrict__ inv) {
    int i = blockIdx.x * blockDim.x + threadIdx.x;   // over B*K*HW/4
    int h4 = (i & (HW_ / 4 - 1)) << 2;
    int bk = i >> 10;
    const float* p = refs + (size_t)bk * C_ * HW_ + h4;
    f32x4 ss = 0.f;
#pragma unroll 8
    for (int c = 0; c < C_; ++c) {
        f32x4 v = *(const f32x4*)(p + (size_t)c * HW_);
        ss += v * v;
    }
    f32x4 o;
#pragma unroll
    for (int j = 0; j < 4; ++j) o[j] = 1.0f / fmaxf(sqrtf(ss[j]), 1e-12f);
    *(f32x4*)(inv + (size_t)bk * HW_ + h4) = o;
}

// ---------------------------------------------------------------------------
// Kernel 0: pre-split NORMALIZED refs into bf16 hi/lo pair planes,
// float4-vectorized (each thread: one (bk,cg) x 4 h). refs is L3-hot after
// norm_kernel. Writes 4 consecutive u32x4 per plane = 64B, coalesced.
// ---------------------------------------------------------------------------
__global__ void presplit_kernel(const float* __restrict__ refs,
                                const float* __restrict__ inv,
                                u32x4* __restrict__ Ghi,
                                u32x4* __restrict__ Glo) {
    int i = blockIdx.x * blockDim.x + threadIdx.x;   // over B*K*16*HW/4
    int h4 = (i & (HW_ / 4 - 1)) << 2;
    int cg = (i >> 10) & 15;
    int bk = i >> 14;
    f32x4 iv = *(const f32x4*)(inv + (size_t)bk * HW_ + h4);
    const float* p = refs + ((size_t)bk * C_ + cg * 8) * HW_ + h4;
    f32x4 vv[8];
#pragma unroll
    for (int m = 0; m < 8; ++m)
        vv[m] = *(const f32x4*)(p + (size_t)m * HW_);
#pragma unroll
    for (int j = 0; j < 4; ++j) {
        u32x4 H, L;
#pragma unroll
        for (int m = 0; m < 4; ++m) {
            unsigned hp, lp;
            split2(vv[2*m][j] * iv[j], vv[2*m+1][j] * iv[j], hp, lp);
            H[m] = hp; L[m] = lp;
        }
        size_t o = (size_t)(bk * 16 + cg) * HW_ + h4 + j;
        Ghi[o] = H;
        Glo[o] = L;
    }
}

// ---------------------------------------------------------------------------
// Kernel 2: gather query vectors; write raw (A, for emul/fuse) and
// L2-normalized (A2, for the GEMM — per-q positive scale, argmax-invariant).
// ---------------------------------------------------------------------------
__global__ void aprep2_kernel(const float* __restrict__ feat,
                              const int* __restrict__ fidx,
                              float* __restrict__ A,
                              float* __restrict__ A2) {
    int w    = (blockIdx.x * blockDim.x + threadIdx.x) >> 6;  // bq
    int lane = threadIdx.x & 63;
    int fi = fidx[w];
    int b  = w >> 11;
    const float* src = feat + (size_t)b * C_ * HW_ + fi;
    float v0 = src[(size_t)lane * HW_];
    float v1 = src[(size_t)(lane + 64) * HW_];
    float ss = fmaf(v0, v0, v1 * v1);
#pragma unroll
    for (int off = 32; off; off >>= 1) ss += __shfl_xor(ss, off);
    float rn = 1.0f / fmaxf(sqrtf(ss), 1e-12f);
    size_t o = (size_t)w * C_;
    A[o + lane]       = v0;
    A[o + lane + 64]  = v1;
    A2[o + lane]      = v0 * rn;
    A2[o + lane + 64] = v1 * rn;
}

// ---------------------------------------------------------------------------
// Kernel 3: split-bf16 3-pass MFMA GEMM, h-SPLIT (verbatim from round 12:
// 282 us, MfmaUtil 63%).
// ---------------------------------------------------------------------------
__global__ __launch_bounds__(256, 4) void gemm_gll_topk2(
        const float* __restrict__ A2,
        const u32x4* __restrict__ Ghi, const u32x4* __restrict__ Glo,
        const int* __restrict__ pindex,
        uint4* __restrict__ kbuf) {
    __shared__ u32x4 Bsh[2][2][512];   // 32 KiB: [buf][plane][cg*32+h]

    const int tid = threadIdx.x;
    const int l = tid & 63, wq = tid >> 6;
    const int ll = l & 15, lh = l >> 4;

    // XCD swizzle: 224 consecutive work-ids (7 pairs x 32 subtiles) per XCD
    int bid = blockIdx.x;
    int swz = (bid & 7) * 224 + (bid >> 3);
    int pair = swz >> 5;
    int rem  = swz & 31;
    int qt = rem >> 1, hs = rem & 1;
    int b = pair / N_, n = pair % N_;
    int index = pindex[0];
    int ks = n + (n >= index ? 1 : 0);
    const int hbase0 = hs * 2048;

    const float* Ap = A2 + ((size_t)b * NUM_ + qt * 128 + wq * 32) * C_;
    const u32x4* Gh = Ghi + (size_t)(b * K_ + ks) * 16 * HW_ + hbase0;
    const u32x4* Gl = Glo + (size_t)(b * K_ + ks) * 16 * HW_ + hbase0;

    // ---- A fragments (hi/lo split of normalized q), persistent ----
    bf16x8 ahi[2][4], alo[2][4];
#pragma unroll
    for (int mf = 0; mf < 2; ++mf)
#pragma unroll
        for (int kk = 0; kk < 4; ++kk) {
            const float* ap = Ap + (mf * 16 + ll) * C_ + kk * 32 + lh * 8;
            float4 xa = *(const float4*)ap;
            float4 xb = *(const float4*)(ap + 4);
            float xs[8] = {xa.x, xa.y, xa.z, xa.w, xb.x, xb.y, xb.z, xb.w};
            u32x4 H, L;
#pragma unroll
            for (int p = 0; p < 4; ++p) {
                unsigned hp, lp;
                split2(xs[2*p], xs[2*p+1], hp, lp);
                H[p] = hp; L[p] = lp;
            }
            ahi[mf][kk] = __builtin_bit_cast(bf16x8, H);
            alo[mf][kk] = __builtin_bit_cast(bf16x8, L);
        }

    // ---- per-lane packed-key top-2 per q-row (8 rows) ----
    unsigned k1[8], k2[8];
#pragma unroll
    for (int rw = 0; rw < 8; ++rw) { k1[rw] = 0u; k2[rw] = 0u; }

    // ---- gll staging map: call j stages linear idx j*256+tid ----
    const int lin0 = tid, lin1 = 256 + tid;
    const size_t go0 = (size_t)(lin0 >> 5) * HW_ + (lin0 & 31);
    const size_t go1 = (size_t)(lin1 >> 5) * HW_ + (lin1 & 31);

#define STAGE(buf, htv) do {                                   \
        gll16(Gh + go0 + (htv), &Bsh[buf][0][lin0]);           \
        gll16(Gh + go1 + (htv), &Bsh[buf][0][lin1]);           \
        gll16(Gl + go0 + (htv), &Bsh[buf][1][lin0]);           \
        gll16(Gl + go1 + (htv), &Bsh[buf][1][lin1]);           \
    } while (0)

    STAGE(0, 0);
    __syncthreads();   // vmcnt(0) drain inserted by compiler

    for (int t = 0; t < 64; ++t) {
        const int cur = t & 1;
        const int ht = t * 32;

        // issue next tile into the other buffer; ages behind MFMA below
        if (t < 63) STAGE(cur ^ 1, ht + 32);

        // ---- 3-pass MFMA: acc = 6 + Ah*Bh + Ah*Bl + Al*Bh ----
        f32x4 acc[2][2];
#pragma unroll
        for (int mf = 0; mf < 2; ++mf)
#pragma unroll
            for (int nf = 0; nf < 2; ++nf) acc[mf][nf] = 6.0f;

#pragma unroll
        for (int kk = 0; kk < 4; ++kk) {
#pragma unroll
            for (int nf = 0; nf < 2; ++nf) {
                int off = (kk * 4 + lh) * 32 + nf * 16 + ll;
                bf16x8 bh = __builtin_bit_cast(bf16x8, Bsh[cur][0][off]);
                bf16x8 bl = __builtin_bit_cast(bf16x8, Bsh[cur][1][off]);
#pragma unroll
                for (int mf = 0; mf < 2; ++mf) {
                    f32x4 a_ = acc[mf][nf];
                    a_ = mf16(ahi[mf][kk], bh, a_);
                    a_ = mf16(ahi[mf][kk], bl, a_);
                    a_ = mf16(alo[mf][kk], bh, a_);
                    acc[mf][nf] = a_;
                }
            }
        }

        // ---- packed-key top-2 (branchless, 5 VALU/elem) ----
#pragma unroll
        for (int nf = 0; nf < 2; ++nf) {
            unsigned hv = (unsigned)(hbase0 + ht + nf * 16 + ll);
#pragma unroll
            for (int mf = 0; mf < 2; ++mf)
#pragma unroll
                for (int r = 0; r < 4; ++r) {
                    int rw = mf * 4 + r;
                    unsigned u = __float_as_uint(acc[mf][nf][r]);
                    unsigned key = ((u & 0x007FFFF8u) << 9) | hv;
                    unsigned mn = min(k1[rw], key);
                    k1[rw] = max(k1[rw], key);
                    k2[rw] = max(k2[rw], mn);
                }
        }

        __syncthreads();   // next tile staged + all reads of cur done
    }
#undef STAGE

    // ---- 16-lane bitonic merge of (k1,k2) -> per-half top-4 keys ----
#define CEU(X,Y) { if (mv[Y] > mv[X]) { unsigned t_ = mv[X]; mv[X] = mv[Y]; mv[Y] = t_; } }
#pragma unroll
    for (int rw = 0; rw < 8; ++rw) {
        unsigned av[4] = {k1[rw], k2[rw], 0u, 0u};
#pragma unroll
        for (int s = 1; s <= 8; s <<= 1) {
            unsigned bv[4];
#pragma unroll
            for (int j = 0; j < 4; ++j)
                bv[j] = (unsigned)__shfl_xor((int)av[j], s);
            unsigned mv[4];
#pragma unroll
            for (int j = 0; j < 4; ++j)
                mv[j] = (av[j] > bv[3-j]) ? av[j] : bv[3-j];
            CEU(0, 2) CEU(1, 3) CEU(0, 1) CEU(2, 3)
#pragma unroll
            for (int j = 0; j < 4; ++j) av[j] = mv[j];
        }
        if (ll == 0) {
            int q = qt * 128 + wq * 32 + (rw >> 2) * 16 + lh * 4 + (rw & 3);
            size_t o = ((size_t)(b * N_ + n) * NUM_ + q) * 2 + hs;
            kbuf[o] = make_uint4(av[0], av[1], av[2], av[3]);
        }
    }
#undef CEU
}

// ---------------------------------------------------------------------------
// numpy pairwise sum (n=128) — verbatim rounding from the passing round-6
// kernel.
// ---------------------------------------------------------------------------
static __device__ float pairwise128_sumsq_div(const float* __restrict__ x,
                                              float d) {
    float r[8];
#pragma unroll
    for (int j = 0; j < 8; ++j) {
        float v = __fdiv_rn(x[j], d);
        r[j] = fmul_nc(v, v);
    }
    for (int i = 8; i < C_; i += 8) {
#pragma unroll
        for (int j = 0; j < 8; ++j) {
            float v = __fdiv_rn(x[i + j], d);
            r[j] = fadd_nc(r[j], fmul_nc(v, v));
        }
    }
    return fadd_nc(fadd_nc(fadd_nc(r[0], r[1]), fadd_nc(r[2], r[3])),
                   fadd_nc(fadd_nc(r[4], r[5]), fadd_nc(r[6], r[7])));
}

// ---------------------------------------------------------------------------
// Emulated numpy score — arithmetic verbatim from round 6; ref column is
// batch-loaded into registers first (one L3 latency, not 128 serial).
// ---------------------------------------------------------------------------
static __device__ float emul_score_batched(const float* __restrict__ w2a,
                                           const float* __restrict__ Rb,
                                           int h) {
    float rv[C_];
#pragma unroll
    for (int c = 0; c < C_; ++c) rv[c] = Rb[(size_t)c * HW_ + h];
    float sr = fmul_nc(rv[0], rv[0]);
#pragma unroll
    for (int c = 1; c < C_; ++c)
        sr = fadd_nc(sr, fmul_nc(rv[c], rv[c]));    // non-FMA, ascending c
    float nr = fmaxf(__fsqrt_rn(sr), 1e-12f);
    float acc = 0.f;
#pragma unroll
    for (int c = 0; c < C_; ++c) {
        float wr = __fdiv_rn(rv[c], nr);
        acc = fadd_nc(acc, fmul_nc(w2a[c], wr));    // non-FMA, ascending c
    }
    return acc;
}

// ---------------------------------------------------------------------------
// Kernel 3b: adjudicate the union of both halves' top-4 (8 candidates).
// Global prune on top1-top2 gap; on near-tie, emulate ONLY the candidates
// within the threshold window of split-top1 (others cannot win: window
// 6.5e-5 >> 2x(split+emul) error ~8e-6). Lowest-index tie-break.
// ---------------------------------------------------------------------------
__global__ __launch_bounds__(256, 1) void rescore_emul8(
        const float* __restrict__ A,
        const float* __restrict__ refs,
        const int* __restrict__ pindex,
        const uint4* __restrict__ kbuf,
        float thr,
        int* __restrict__ idxout,
        float* __restrict__ out2) {
    int r = blockIdx.x * blockDim.x + threadIdx.x;   // over B*N*NUM
    if (r >= B_ * N_ * NUM_) return;
    uint4 ka = kbuf[(size_t)r * 2 + 0];
    uint4 kb = kbuf[(size_t)r * 2 + 1];
    unsigned kk[8] = {ka.x, ka.y, ka.z, ka.w, kb.x, kb.y, kb.z, kb.w};
    unsigned s1 = 0u, s2 = 0u;
#pragma unroll
    for (int j = 0; j < 8; ++j) {
        unsigned mn = min(s1, kk[j]);
        s1 = max(s1, kk[j]);
        s2 = max(s2, mn);
    }
    int win;
    unsigned top = s1 >> 12;
    if ((float)(top - (s2 >> 12)) > thr) {
        win = (int)(s1 & 0xFFFu);
    } else {
        int q  = r & (NUM_ - 1);
        int bn = r >> 11;
        int b = bn / N_, n = bn % N_;
        int index = pindex[0];
        int ks = n + (n >= index ? 1 : 0);
        const float* qp = A    + ((size_t)b * NUM_ + q) * C_;
        const float* Rb = refs + (size_t)(b * K_ + ks) * C_ * HW_;
        float s1f = pairwise128_sumsq_div(qp, 1.0f);
        float n1 = fmaxf(__fsqrt_rn(s1f), 1e-12f);
        float s2f = pairwise128_sumsq_div(qp, n1);
        float n2 = fmaxf(__fsqrt_rn(s2f), 1e-12f);
        // hoist double-normalized query (verbatim rounding)
        float w2a[C_];
#pragma unroll
        for (int c = 0; c < C_; ++c)
            w2a[c] = __fdiv_rn(__fdiv_rn(qp[c], n1), n2);
        win = -1; float bw = -INFINITY;
        for (int j = 0; j < 8; ++j) {
            if ((float)(top - (kk[j] >> 12)) > thr) continue;  // can't win
            int h = (int)(kk[j] & 0xFFFu);
            float s = emul_score_batched(w2a, Rb, h);
            if (s > bw || (s == bw && h < win)) { bw = s; win = h; }
        }
    }
    idxout[r] = win;
    out2[r]   = (float)win;
}

// ---------------------------------------------------------------------------
// Kernel 4: fused = base_sim*feat_sel + sum_n sims[n]*refs[b,kn,:,idx_n],
// scattered into out[b][c][fi]. Also writes feat_indices output as float.
// ---------------------------------------------------------------------------
__global__ void fuse_scatter(const float* __restrict__ A,
                             const float* __restrict__ refs,
                             const float* __restrict__ sim,
                             const int* __restrict__ fidx,
                             const int* __restrict__ pindex,
                             const int* __restrict__ idxbuf,
                             float* __restrict__ out0,
                             float* __restrict__ out1) {
    int bq = blockIdx.x;                 // over B*NUM
    int q  = bq & (NUM_ - 1);
    int b  = bq >> 11;
    int c  = threadIdx.x;                // 128 threads
    int index = pindex[0];
    int fi = fidx[bq];

    float v = sim[b * K_ + index] * A[(size_t)bq * C_ + c];
#pragma unroll
    for (int n = 0; n < N_; ++n) {
        int ks = n + (n >= index ? 1 : 0);
        int id = idxbuf[(size_t)(b * N_ + n) * NUM_ + q];
        v = fmaf(sim[b * K_ + ks],
                 refs[((size_t)(b * K_ + ks) * C_ + c) * HW_ + id], v);
    }
    out0[((size_t)b * C_ + c) * HW_ + fi] = v;
    if (c == 0) out1[bq] = (float)fi;
}

// ---------------------------------------------------------------------------
extern "C" void kernel_launch(void* const* d_in, const int* in_sizes, int n_in,
                              void* d_out, int out_size, void* d_ws, size_t ws_size,
                              hipStream_t stream) {
    const float* feat = (const float*)d_in[0];   // [B][C][HW]
    const float* refs = (const float*)d_in[1];   // [B][K][C][HW]
    const float* sim  = (const float*)d_in[2];   // [B][K]
    const int*   fidx = (const int*)d_in[3];     // [B][NUM]
    const int*   pidx = (const int*)d_in[4];     // scalar index

    float* wsf   = (float*)d_ws;
    float* A     = wsf + WS_A_OFF;
    float* inv   = wsf + WS_INV_OFF;
    uint4* kbuf  = (uint4*)(wsf + WS_KBUF_OFF);
    int*   idxf  = (int*)(wsf + WS_IDX_OFF);
    float* A2    = wsf + WS_A2_OFF;
    u32x4* Ghi   = (u32x4*)(wsf + WS_GHI_OFF);
    u32x4* Glo   = Ghi + GPLANE_V4;

    float* out0 = (float*)d_out;                       // [B][C][HW]
    float* out1 = out0 + (size_t)B_ * C_ * HW_;        // feat_indices (f32)
    float* out2 = out1 + (size_t)B_ * NUM_;            // ref_indices (f32)

    // inverse norms (float4 loads), then normalized split planes (L3-hot)
    norm_kernel<<<(B_ * K_ * HW_ / 4) / 256, 256, 0, stream>>>(refs, inv);
    presplit_kernel<<<(B_ * K_ * 16 * HW_ / 4) / 256, 256, 0, stream>>>(
        refs, inv, Ghi, Glo);
    aprep2_kernel<<<(B_ * NUM_) / 4, 256, 0, stream>>>(feat, fidx, A, A2);
    hipMemcpyAsync(out0, feat, (size_t)B_ * C_ * HW_ * sizeof(float),
                   hipMemcpyDeviceToDevice, stream);
    // h-split GEMM: 56 pairs x 16 q-tiles x 2 h-halves
    gemm_gll_topk2<<<56 * 16 * 2, 256, 0, stream>>>(A2, Ghi, Glo, pidx, kbuf);
    // prune threshold: 8.5 key units ~ 3.2e-5 in cosine scale
    rescore_emul8<<<(B_ * N_ * NUM_ + 255) / 256, 256, 0, stream>>>(
        A, refs, pidx, kbuf, 8.5f, idxf, out2);
    fuse_scatter<<<B_ * NUM_, 128, 0, stream>>>(A, refs, sim, fidx, pidx,
                                                idxf, out0, out1);
}

// Round 14
// 506.699 us; speedup vs baseline: 1.4417x; 1.3229x over previous
//
#include <hip/hip_runtime.h>
#include <math.h>

#define B_    8
#define K_    8
#define C_    128
#define HW_   4096
#define NUM_  2048
#define N_    7          // K-1 refs used

// ---------------- workspace layout (32-bit words) ----------------
#define WS_A_OFF    0                               // [B][NUM][C] raw q
#define WS_INV_OFF  (B_*NUM_*C_)                    // [B][K][HW] 1/norm; selq overlays after presplit
#define WS_KBUF_OFF (WS_INV_OFF + B_*K_*HW_)        // [B][N][NUM][2] uint4
#define WS_IDX_OFF  (WS_KBUF_OFF + B_*N_*NUM_*8)    // [B][N][NUM] int
#define WS_A2_OFF   (WS_IDX_OFF + B_*N_*NUM_)       // [B][NUM][C] normed q
#define WS_GHI_OFF  (WS_A2_OFF + B_*NUM_*C_)        // split planes; refs_T overlays after GEMM
#define GPLANE_V4   (B_*K_*16*HW_)                  // u32x4 per plane

typedef __bf16 bf16x8 __attribute__((ext_vector_type(8)));
typedef float  f32x4  __attribute__((ext_vector_type(4)));
typedef unsigned int u32x4 __attribute__((ext_vector_type(4)));

static __device__ __forceinline__ f32x4 mf16(bf16x8 a, bf16x8 b, f32x4 c) {
    return __builtin_amdgcn_mfma_f32_16x16x32_bf16(a, b, c, 0, 0, 0);
}

// RTNE bf16 high-part (bit math, branch-free)
static __device__ __forceinline__ unsigned bfhi16(float x) {
    unsigned b = __float_as_uint(x);
    return (b + 0x7fffu + ((b >> 16) & 1u)) >> 16;
}
// split two floats (consecutive c) into packed hi-pair and lo-pair u32
static __device__ __forceinline__ void split2(float x, float y,
                                              unsigned &hp, unsigned &lp) {
    unsigned hx = bfhi16(x), hy = bfhi16(y);
    float rx = x - __uint_as_float(hx << 16);
    float ry = y - __uint_as_float(hy << 16);
    hp = hx | (hy << 16);
    lp = bfhi16(rx) | (bfhi16(ry) << 16);
}

// ---- contraction-proof mul/add (verbatim from the passing round-6 kernel)
static __device__ __forceinline__ float fmul_nc(float a, float b) {
    float r = a * b;
    asm volatile("" : "+v"(r));
    return r;
}
static __device__ __forceinline__ float fadd_nc(float a, float b) {
    float r = a + b;
    asm volatile("" : "+v"(r));
    return r;
}

// async global -> LDS, 16B per lane
static __device__ __forceinline__ void gll16(const u32x4* g, u32x4* l) {
    __builtin_amdgcn_global_load_lds(
        (const __attribute__((address_space(1))) void*)g,
        (__attribute__((address_space(3))) void*)l, 16, 0, 0);
}

// ---------------------------------------------------------------------------
// Kernel 1: inverse L2 norms, float4-vectorized (each thread: 4 h columns).
// ---------------------------------------------------------------------------
__global__ void norm_kernel(const float* __restrict__ refs,
                            float* __restrict__ inv) {
    int i = blockIdx.x * blockDim.x + threadIdx.x;   // over B*K*HW/4
    int h4 = (i & (HW_ / 4 - 1)) << 2;
    int bk = i >> 10;
    const float* p = refs + (size_t)bk * C_ * HW_ + h4;
    f32x4 ss = 0.f;
#pragma unroll 8
    for (int c = 0; c < C_; ++c) {
        f32x4 v = *(const f32x4*)(p + (size_t)c * HW_);
        ss += v * v;
    }
    f32x4 o;
#pragma unroll
    for (int j = 0; j < 4; ++j) o[j] = 1.0f / fmaxf(sqrtf(ss[j]), 1e-12f);
    *(f32x4*)(inv + (size_t)bk * HW_ + h4) = o;
}

// ---------------------------------------------------------------------------
// Kernel 0: pre-split NORMALIZED refs into bf16 hi/lo pair planes,
// float4-vectorized (verbatim from round 13).
// ---------------------------------------------------------------------------
__global__ void presplit_kernel(const float* __restrict__ refs,
                                const float* __restrict__ inv,
                                u32x4* __restrict__ Ghi,
                                u32x4* __restrict__ Glo) {
    int i = blockIdx.x * blockDim.x + threadIdx.x;   // over B*K*16*HW/4
    int h4 = (i & (HW_ / 4 - 1)) << 2;
    int cg = (i >> 10) & 15;
    int bk = i >> 14;
    f32x4 iv = *(const f32x4*)(inv + (size_t)bk * HW_ + h4);
    const float* p = refs + ((size_t)bk * C_ + cg * 8) * HW_ + h4;
    f32x4 vv[8];
#pragma unroll
    for (int m = 0; m < 8; ++m)
        vv[m] = *(const f32x4*)(p + (size_t)m * HW_);
#pragma unroll
    for (int j = 0; j < 4; ++j) {
        u32x4 H, L;
#pragma unroll
        for (int m = 0; m < 4; ++m) {
            unsigned hp, lp;
            split2(vv[2*m][j] * iv[j], vv[2*m+1][j] * iv[j], hp, lp);
            H[m] = hp; L[m] = lp;
        }
        size_t o = (size_t)(bk * 16 + cg) * HW_ + h4 + j;
        Ghi[o] = H;
        Glo[o] = L;
    }
}

// ---------------------------------------------------------------------------
// Kernel 2: gather query vectors; raw (A) + L2-normalized (A2).
// ---------------------------------------------------------------------------
__global__ void aprep2_kernel(const float* __restrict__ feat,
                              const int* __restrict__ fidx,
                              float* __restrict__ A,
                              float* __restrict__ A2) {
    int w    = (blockIdx.x * blockDim.x + threadIdx.x) >> 6;  // bq
    int lane = threadIdx.x & 63;
    int fi = fidx[w];
    int b  = w >> 11;
    const float* src = feat + (size_t)b * C_ * HW_ + fi;
    float v0 = src[(size_t)lane * HW_];
    float v1 = src[(size_t)(lane + 64) * HW_];
    float ss = fmaf(v0, v0, v1 * v1);
#pragma unroll
    for (int off = 32; off; off >>= 1) ss += __shfl_xor(ss, off);
    float rn = 1.0f / fmaxf(sqrtf(ss), 1e-12f);
    size_t o = (size_t)w * C_;
    A[o + lane]       = v0;
    A[o + lane + 64]  = v1;
    A2[o + lane]      = v0 * rn;
    A2[o + lane + 64] = v1 * rn;
}

// ---------------------------------------------------------------------------
// Kernel 2b: build inverse selection map selq[b][h] = q (or -1), and emit
// feat_indices output as float.
// ---------------------------------------------------------------------------
__global__ void selbuild_kernel(const int* __restrict__ fidx,
                                int* __restrict__ selq,
                                float* __restrict__ out1) {
    int bq = blockIdx.x * blockDim.x + threadIdx.x;  // over B*NUM
    int fi = fidx[bq];
    int b  = bq >> 11;
    selq[b * HW_ + fi] = bq & (NUM_ - 1);
    out1[bq] = (float)fi;
}

// ---------------------------------------------------------------------------
// Kernel 3: split-bf16 3-pass MFMA GEMM, h-SPLIT (verbatim from round 12/13:
// 282 us, MfmaUtil 62%).
// ---------------------------------------------------------------------------
__global__ __launch_bounds__(256, 4) void gemm_gll_topk2(
        const float* __restrict__ A2,
        const u32x4* __restrict__ Ghi, const u32x4* __restrict__ Glo,
        const int* __restrict__ pindex,
        uint4* __restrict__ kbuf) {
    __shared__ u32x4 Bsh[2][2][512];   // 32 KiB: [buf][plane][cg*32+h]

    const int tid = threadIdx.x;
    const int l = tid & 63, wq = tid >> 6;
    const int ll = l & 15, lh = l >> 4;

    // XCD swizzle: 224 consecutive work-ids (7 pairs x 32 subtiles) per XCD
    int bid = blockIdx.x;
    int swz = (bid & 7) * 224 + (bid >> 3);
    int pair = swz >> 5;
    int rem  = swz & 31;
    int qt = rem >> 1, hs = rem & 1;
    int b = pair / N_, n = pair % N_;
    int index = pindex[0];
    int ks = n + (n >= index ? 1 : 0);
    const int hbase0 = hs * 2048;

    const float* Ap = A2 + ((size_t)b * NUM_ + qt * 128 + wq * 32) * C_;
    const u32x4* Gh = Ghi + (size_t)(b * K_ + ks) * 16 * HW_ + hbase0;
    const u32x4* Gl = Glo + (size_t)(b * K_ + ks) * 16 * HW_ + hbase0;

    // ---- A fragments (hi/lo split of normalized q), persistent ----
    bf16x8 ahi[2][4], alo[2][4];
#pragma unroll
    for (int mf = 0; mf < 2; ++mf)
#pragma unroll
        for (int kk = 0; kk < 4; ++kk) {
            const float* ap = Ap + (mf * 16 + ll) * C_ + kk * 32 + lh * 8;
            float4 xa = *(const float4*)ap;
            float4 xb = *(const float4*)(ap + 4);
            float xs[8] = {xa.x, xa.y, xa.z, xa.w, xb.x, xb.y, xb.z, xb.w};
            u32x4 H, L;
#pragma unroll
            for (int p = 0; p < 4; ++p) {
                unsigned hp, lp;
                split2(xs[2*p], xs[2*p+1], hp, lp);
                H[p] = hp; L[p] = lp;
            }
            ahi[mf][kk] = __builtin_bit_cast(bf16x8, H);
            alo[mf][kk] = __builtin_bit_cast(bf16x8, L);
        }

    // ---- per-lane packed-key top-2 per q-row (8 rows) ----
    unsigned k1[8], k2[8];
#pragma unroll
    for (int rw = 0; rw < 8; ++rw) { k1[rw] = 0u; k2[rw] = 0u; }

    // ---- gll staging map: call j stages linear idx j*256+tid ----
    const int lin0 = tid, lin1 = 256 + tid;
    const size_t go0 = (size_t)(lin0 >> 5) * HW_ + (lin0 & 31);
    const size_t go1 = (size_t)(lin1 >> 5) * HW_ + (lin1 & 31);

#define STAGE(buf, htv) do {                                   \
        gll16(Gh + go0 + (htv), &Bsh[buf][0][lin0]);           \
        gll16(Gh + go1 + (htv), &Bsh[buf][0][lin1]);           \
        gll16(Gl + go0 + (htv), &Bsh[buf][1][lin0]);           \
        gll16(Gl + go1 + (htv), &Bsh[buf][1][lin1]);           \
    } while (0)

    STAGE(0, 0);
    __syncthreads();   // vmcnt(0) drain inserted by compiler

    for (int t = 0; t < 64; ++t) {
        const int cur = t & 1;
        const int ht = t * 32;

        // issue next tile into the other buffer; ages behind MFMA below
        if (t < 63) STAGE(cur ^ 1, ht + 32);

        // ---- 3-pass MFMA: acc = 6 + Ah*Bh + Ah*Bl + Al*Bh ----
        f32x4 acc[2][2];
#pragma unroll
        for (int mf = 0; mf < 2; ++mf)
#pragma unroll
            for (int nf = 0; nf < 2; ++nf) acc[mf][nf] = 6.0f;

#pragma unroll
        for (int kk = 0; kk < 4; ++kk) {
#pragma unroll
            for (int nf = 0; nf < 2; ++nf) {
                int off = (kk * 4 + lh) * 32 + nf * 16 + ll;
                bf16x8 bh = __builtin_bit_cast(bf16x8, Bsh[cur][0][off]);
                bf16x8 bl = __builtin_bit_cast(bf16x8, Bsh[cur][1][off]);
#pragma unroll
                for (int mf = 0; mf < 2; ++mf) {
                    f32x4 a_ = acc[mf][nf];
                    a_ = mf16(ahi[mf][kk], bh, a_);
                    a_ = mf16(ahi[mf][kk], bl, a_);
                    a_ = mf16(alo[mf][kk], bh, a_);
                    acc[mf][nf] = a_;
                }
            }
        }

        // ---- packed-key top-2 (branchless, 5 VALU/elem) ----
#pragma unroll
        for (int nf = 0; nf < 2; ++nf) {
            unsigned hv = (unsigned)(hbase0 + ht + nf * 16 + ll);
#pragma unroll
            for (int mf = 0; mf < 2; ++mf)
#pragma unroll
                for (int r = 0; r < 4; ++r) {
                    int rw = mf * 4 + r;
                    unsigned u = __float_as_uint(acc[mf][nf][r]);
                    unsigned key = ((u & 0x007FFFF8u) << 9) | hv;
                    unsigned mn = min(k1[rw], key);
                    k1[rw] = max(k1[rw], key);
                    k2[rw] = max(k2[rw], mn);
                }
        }

        __syncthreads();   // next tile staged + all reads of cur done
    }
#undef STAGE

    // ---- 16-lane bitonic merge of (k1,k2) -> per-half top-4 keys ----
#define CEU(X,Y) { if (mv[Y] > mv[X]) { unsigned t_ = mv[X]; mv[X] = mv[Y]; mv[Y] = t_; } }
#pragma unroll
    for (int rw = 0; rw < 8; ++rw) {
        unsigned av[4] = {k1[rw], k2[rw], 0u, 0u};
#pragma unroll
        for (int s = 1; s <= 8; s <<= 1) {
            unsigned bv[4];
#pragma unroll
            for (int j = 0; j < 4; ++j)
                bv[j] = (unsigned)__shfl_xor((int)av[j], s);
            unsigned mv[4];
#pragma unroll
            for (int j = 0; j < 4; ++j)
                mv[j] = (av[j] > bv[3-j]) ? av[j] : bv[3-j];
            CEU(0, 2) CEU(1, 3) CEU(0, 1) CEU(2, 3)
#pragma unroll
            for (int j = 0; j < 4; ++j) av[j] = mv[j];
        }
        if (ll == 0) {
            int q = qt * 128 + wq * 32 + (rw >> 2) * 16 + lh * 4 + (rw & 3);
            size_t o = ((size_t)(b * N_ + n) * NUM_ + q) * 2 + hs;
            kbuf[o] = make_uint4(av[0], av[1], av[2], av[3]);
        }
    }
#undef CEU
}

// ---------------------------------------------------------------------------
// Kernel 5: LDS-tiled transpose refs[bk][c][h] -> refs_T[bk][h][c].
// Runs AFTER the GEMM; refs_T overlays the then-dead split planes.
// ---------------------------------------------------------------------------
__global__ void transpose_refs(const float* __restrict__ refs,
                               float* __restrict__ refsT) {
    __shared__ float t[32][33];
    int bid = blockIdx.x;
    int ht = bid & 127;
    int ct = (bid >> 7) & 3;
    int bk = bid >> 9;
    int tx = threadIdx.x & 31, ty = threadIdx.x >> 5;  // ty 0..7
    const float* src = refs + ((size_t)bk * C_ + ct * 32) * HW_ + ht * 32;
#pragma unroll
    for (int j = 0; j < 4; ++j)
        t[ty + 8 * j][tx] = src[(size_t)(ty + 8 * j) * HW_ + tx];
    __syncthreads();
    float* dst = refsT + ((size_t)bk * HW_ + ht * 32) * C_ + ct * 32;
#pragma unroll
    for (int j = 0; j < 4; ++j)
        dst[(size_t)(ty + 8 * j) * C_ + tx] = t[tx][ty + 8 * j];
}

// ---------------------------------------------------------------------------
// numpy pairwise sum (n=128) — verbatim rounding from the passing round-6
// kernel.
// ---------------------------------------------------------------------------
static __device__ float pairwise128_sumsq_div(const float* __restrict__ x,
                                              float d) {
    float r[8];
#pragma unroll
    for (int j = 0; j < 8; ++j) {
        float v = __fdiv_rn(x[j], d);
        r[j] = fmul_nc(v, v);
    }
    for (int i = 8; i < C_; i += 8) {
#pragma unroll
        for (int j = 0; j < 8; ++j) {
            float v = __fdiv_rn(x[i + j], d);
            r[j] = fadd_nc(r[j], fmul_nc(v, v));
        }
    }
    return fadd_nc(fadd_nc(fadd_nc(r[0], r[1]), fadd_nc(r[2], r[3])),
                   fadd_nc(fadd_nc(r[4], r[5]), fadd_nc(r[6], r[7])));
}

// ---------------------------------------------------------------------------
// Emulated numpy score from a TRANSPOSED ref row (identical float values,
// identical rounding chains; loads are now 128 consecutive floats).
// ---------------------------------------------------------------------------
static __device__ float emul_score_T(const float* __restrict__ w2a,
                                     const float* __restrict__ row) {
    float rv[C_];
#pragma unroll
    for (int c = 0; c < C_; ++c) rv[c] = row[c];
    float sr = fmul_nc(rv[0], rv[0]);
#pragma unroll
    for (int c = 1; c < C_; ++c)
        sr = fadd_nc(sr, fmul_nc(rv[c], rv[c]));    // non-FMA, ascending c
    float nr = fmaxf(__fsqrt_rn(sr), 1e-12f);
    float acc = 0.f;
#pragma unroll
    for (int c = 0; c < C_; ++c) {
        float wr = __fdiv_rn(rv[c], nr);
        acc = fadd_nc(acc, fmul_nc(w2a[c], wr));    // non-FMA, ascending c
    }
    return acc;
}

// ---------------------------------------------------------------------------
// Kernel 3b: adjudicate the union of both halves' top-4 (8 candidates).
// Global prune on top1-top2 gap; on near-tie, emulate ONLY candidates within
// the window of split-top1. Lowest-index tie-break.
// ---------------------------------------------------------------------------
__global__ __launch_bounds__(256, 1) void rescore_emul8(
        const float* __restrict__ A,
        const float* __restrict__ refsT,
        const int* __restrict__ pindex,
        const uint4* __restrict__ kbuf,
        float thr,
        int* __restrict__ idxout,
        float* __restrict__ out2) {
    int r = blockIdx.x * blockDim.x + threadIdx.x;   // over B*N*NUM
    if (r >= B_ * N_ * NUM_) return;
    uint4 ka = kbuf[(size_t)r * 2 + 0];
    uint4 kb = kbuf[(size_t)r * 2 + 1];
    unsigned kk[8] = {ka.x, ka.y, ka.z, ka.w, kb.x, kb.y, kb.z, kb.w};
    unsigned s1 = 0u, s2 = 0u;
#pragma unroll
    for (int j = 0; j < 8; ++j) {
        unsigned mn = min(s1, kk[j]);
        s1 = max(s1, kk[j]);
        s2 = max(s2, mn);
    }
    int win;
    unsigned top = s1 >> 12;
    if ((float)(top - (s2 >> 12)) > thr) {
        win = (int)(s1 & 0xFFFu);
    } else {
        int q  = r & (NUM_ - 1);
        int bn = r >> 11;
        int b = bn / N_, n = bn % N_;
        int index = pindex[0];
        int ks = n + (n >= index ? 1 : 0);
        const float* qp  = A     + ((size_t)b * NUM_ + q) * C_;
        const float* RbT = refsT + (size_t)(b * K_ + ks) * HW_ * C_;
        float s1f = pairwise128_sumsq_div(qp, 1.0f);
        float n1 = fmaxf(__fsqrt_rn(s1f), 1e-12f);
        float s2f = pairwise128_sumsq_div(qp, n1);
        float n2 = fmaxf(__fsqrt_rn(s2f), 1e-12f);
        // hoist double-normalized query (verbatim rounding)
        float w2a[C_];
#pragma unroll
        for (int c = 0; c < C_; ++c)
            w2a[c] = __fdiv_rn(__fdiv_rn(qp[c], n1), n2);
        win = -1; float bw = -INFINITY;
        for (int j = 0; j < 8; ++j) {
            if ((float)(top - (kk[j] >> 12)) > thr) continue;  // can't win
            int h = (int)(kk[j] & 0xFFFu);
            float s = emul_score_T(w2a, RbT + (size_t)h * C_);
            if (s > bw || (s == bw && h < win)) { bw = s; win = h; }
        }
    }
    idxout[r] = win;
    out2[r]   = (float)win;
}

// ---------------------------------------------------------------------------
// Kernel 4: fused copy+scatter. Thread per (b,c,4h): coalesced feat read and
// out0 write; selected columns (selq) get the fused value from refs_T rows.
// Replaces the 268 MB memcpy AND the scattered-write fuse_scatter pass.
// ---------------------------------------------------------------------------
__global__ void fused_copy_scatter(const float* __restrict__ feat,
                                   const float* __restrict__ refsT,
                                   const float* __restrict__ sim,
                                   const int* __restrict__ selq,
                                   const int* __restrict__ pindex,
                                   const int* __restrict__ idxf,
                                   float* __restrict__ out0) {
    int i = blockIdx.x * blockDim.x + threadIdx.x;   // over B*C*HW/4
    int h4 = (i & (HW_ / 4 - 1)) << 2;
    int c  = (i >> 10) & (C_ - 1);
    int b  = i >> 17;
    size_t off = ((size_t)b * C_ + c) * HW_ + h4;
    f32x4 v = *(const f32x4*)(feat + off);
    int4 q4 = *(const int4*)(selq + b * HW_ + h4);
    int qs[4] = {q4.x, q4.y, q4.z, q4.w};
    if ((qs[0] | qs[1] | qs[2] | qs[3]) != -1 &&
        (qs[0] >= 0 || qs[1] >= 0 || qs[2] >= 0 || qs[3] >= 0)) {
        int index = pindex[0];
        float bs = sim[b * K_ + index];
        const float* rT = refsT + (size_t)b * K_ * HW_ * C_ + c;
#pragma unroll
        for (int j = 0; j < 4; ++j) {
            if (qs[j] < 0) continue;
            float acc = bs * v[j];
#pragma unroll
            for (int n = 0; n < N_; ++n) {
                int ks = n + (n >= index ? 1 : 0);
                int id = idxf[(size_t)(b * N_ + n) * NUM_ + qs[j]];
                acc = fmaf(sim[b * K_ + ks],
                           rT[((size_t)ks * HW_ + id) * C_], acc);
            }
            v[j] = acc;
        }
    }
    *(f32x4*)(out0 + off) = v;
}

// ---------------------------------------------------------------------------
extern "C" void kernel_launch(void* const* d_in, const int* in_sizes, int n_in,
                              void* d_out, int out_size, void* d_ws, size_t ws_size,
                              hipStream_t stream) {
    const float* feat = (const float*)d_in[0];   // [B][C][HW]
    const float* refs = (const float*)d_in[1];   // [B][K][C][HW]
    const float* sim  = (const float*)d_in[2];   // [B][K]
    const int*   fidx = (const int*)d_in[3];     // [B][NUM]
    const int*   pidx = (const int*)d_in[4];     // scalar index

    float* wsf   = (float*)d_ws;
    float* A     = wsf + WS_A_OFF;
    float* inv   = wsf + WS_INV_OFF;
    int*   selq  = (int*)(wsf + WS_INV_OFF);     // overlays inv after presplit
    uint4* kbuf  = (uint4*)(wsf + WS_KBUF_OFF);
    int*   idxf  = (int*)(wsf + WS_IDX_OFF);
    float* A2    = wsf + WS_A2_OFF;
    u32x4* Ghi   = (u32x4*)(wsf + WS_GHI_OFF);
    u32x4* Glo   = Ghi + GPLANE_V4;
    float* refsT = (float*)Ghi;                  // overlays planes after GEMM

    float* out0 = (float*)d_out;                       // [B][C][HW]
    float* out1 = out0 + (size_t)B_ * C_ * HW_;        // feat_indices (f32)
    float* out2 = out1 + (size_t)B_ * NUM_;            // ref_indices (f32)

    // inverse norms (float4 loads), then normalized split planes (L3-hot)
    norm_kernel<<<(B_ * K_ * HW_ / 4) / 256, 256, 0, stream>>>(refs, inv);
    presplit_kernel<<<(B_ * K_ * 16 * HW_ / 4) / 256, 256, 0, stream>>>(
        refs, inv, Ghi, Glo);
    aprep2_kernel<<<(B_ * NUM_) / 4, 256, 0, stream>>>(feat, fidx, A, A2);
    // selq = -1 everywhere, then scatter q indices; also emits out1
    hipMemsetAsync(selq, 0xFF, (size_t)B_ * HW_ * sizeof(int), stream);
    selbuild_kernel<<<(B_ * NUM_) / 256, 256, 0, stream>>>(fidx, selq, out1);
    // h-split GEMM: 56 pairs x 16 q-tiles x 2 h-halves
    gemm_gll_topk2<<<56 * 16 * 2, 256, 0, stream>>>(A2, Ghi, Glo, pidx, kbuf);
    // transpose refs into the now-dead plane region
    transpose_refs<<<B_ * K_ * 4 * (HW_ / 32), 256, 0, stream>>>(refs, refsT);
    // prune threshold: 8.5 key units ~ 3.2e-5 in cosine scale
    rescore_emul8<<<(B_ * N_ * NUM_ + 255) / 256, 256, 0, stream>>>(
        A, refsT, pidx, kbuf, 8.5f, idxf, out2);
    // fused full copy + scatter of fused columns (coalesced writes)
    fused_copy_scatter<<<(B_ * C_ * HW_ / 4) / 256, 256, 0, stream>>>(
        feat, refsT, sim, selq, pidx, idxf, out0);
}